// Round 5
// baseline (223.846 us; speedup 1.0000x reference)
//
#include <hip/hip_runtime.h>
#include <math.h>

#define NBINS 513
#define NROWS 4000
#define BATCH 8
#define FPW   4                       // output rows per chain (one wave owns a chain)
#define CPB   2                       // chains (waves) per block
#define CHAINS_PER_BATCH (NROWS / FPW)   // 1000

__device__ __forceinline__ void cmul(float& ar, float& ai, float br, float bi) {
    const float t = ar * br - ai * bi;
    ai = ar * bi + ai * br;
    ar = t;
}

// In-place inverse DFT-8 (omega = e^{+2pi i/8}) on 8 complex register values.
__device__ __forceinline__ void idft8(float* xr, float* xi) {
    const float S = 0.70710678118654752440f;
    float er[4], ei[4], orr[4], oi[4];
    #pragma unroll
    for (int j = 0; j < 4; ++j) {
        er[j]  = xr[j] + xr[j+4];  ei[j] = xi[j] + xi[j+4];
        orr[j] = xr[j] - xr[j+4];  oi[j] = xi[j] - xi[j+4];
    }
    const float f1r = S * (orr[1] - oi[1]), f1i = S * (orr[1] + oi[1]);
    const float f2r = -oi[2],               f2i = orr[2];
    const float f3r = S * (-orr[3] - oi[3]), f3i = S * (orr[3] - oi[3]);
    {   // DFT4 (w4 = +i) over evens -> y0,y2,y4,y6
        const float eer = er[0]+er[2], eei = ei[0]+ei[2];
        const float eor = er[0]-er[2], eoi = ei[0]-ei[2];
        const float oer = er[1]+er[3], oei = ei[1]+ei[3];
        const float oor = er[1]-er[3], ooi = ei[1]-ei[3];
        xr[0] = eer + oer;  xi[0] = eei + oei;
        xr[2] = eor - ooi;  xi[2] = eoi + oor;
        xr[4] = eer - oer;  xi[4] = eei - oei;
        xr[6] = eor + ooi;  xi[6] = eoi - oor;
    }
    {   // DFT4 over odds*w8 -> y1,y3,y5,y7
        const float eer = orr[0]+f2r, eei = oi[0]+f2i;
        const float eor = orr[0]-f2r, eoi = oi[0]-f2i;
        const float oer = f1r+f3r,    oei = f1i+f3i;
        const float oor = f1r-f3r,    ooi = f1i-f3i;
        xr[1] = eer + oer;  xi[1] = eei + oei;
        xr[3] = eor - ooi;  xi[3] = eoi + oor;
        xr[5] = eer - oer;  xi[5] = eei - oei;
        xr[7] = eor + ooi;  xi[7] = eoi - oor;
    }
}

__global__ __launch_bounds__(128, 5) void istft_kernel(
    const float* __restrict__ re, const float* __restrict__ im,
    float* __restrict__ out)
{
    __shared__ float2 ex2[CPB][512];   // wave-private exchange regions

    const int tid = threadIdx.x;
    const int u   = tid & 63;
    const int g   = tid >> 6;
    const int b   = blockIdx.y;
    const int chain = blockIdx.x * CPB + g;       // 0..999
    const int t0  = chain * FPW;

    const int k1 = u >> 3;
    const int k2 = u & 7;

    // ---- loop-invariant per-thread twiddles (registers, no LDS table) ----
    const float w0 = 6.283185307179586476925f / 1024.0f;
    float2 twp[8];
    #pragma unroll
    for (int j = 0; j < 8; ++j) {
        float s, c; sincosf(w0 * (float)(u + 64 * j), &s, &c);
        twp[j] = make_float2(c, s);
    }
    float2 wA, wB0, wBs;
    {
        float s, c;
        sincosf(w0 * (float)(16 * k1), &s, &c);     wA  = make_float2(c, s);
        sincosf(w0 * (float)(2 * k2 * k1), &s, &c); wB0 = make_float2(c, s);
        sincosf(w0 * (float)(16 * k2), &s, &c);     wBs = make_float2(c, s);
    }

    float2 cc[4];                      // OLA carry — wave-private registers
    #pragma unroll
    for (int m = 0; m < 4; ++m) cc[m] = make_float2(0.f, 0.f);

    for (int t = t0 - 1; t < t0 + FPW; ++t) {
        // ---- pack: Z[u+64j] = Xe + i*w1024^k*Xo, scaled by 0.5/1024 ----
        float zr8[8], zi8[8];
        if (t >= 0) {
            const size_t base = ((size_t)b * NROWS + (size_t)t) * NBINS;
            const float* rp = re + base;
            const float* ip = im + base;
            const float F = 4.8828125e-4f;   // 0.5 * (1/1024)
            #pragma unroll
            for (int j = 0; j < 8; ++j) {
                const int k = u + 64 * j;
                float xr = rp[k], xi = ip[k];
                float rc, ic;
                if (k == 0) { xi = 0.f; rc = rp[512]; ic = 0.f; }  // pocketfft c2r
                else        { rc = rp[512 - k]; ic = -ip[512 - k]; }
                const float er = F * (xr + rc), ei = F * (xi + ic);
                const float hr = F * (xr - rc), hi = F * (xi - ic);
                const float o_r = twp[j].x * hr - twp[j].y * hi;
                const float o_i = twp[j].x * hi + twp[j].y * hr;
                zr8[j] = er - o_i;
                zi8[j] = ei + o_r;
            }
        } else {
            #pragma unroll
            for (int j = 0; j < 8; ++j) { zr8[j] = 0.f; zi8[j] = 0.f; }
        }

        // ---- stage A: IDFT8 over the 64s digit, twiddle w64^(k1*m0) ----
        idft8(zr8, zi8);
        {
            float tr = wA.x, ti = wA.y;
            #pragma unroll
            for (int m0 = 1; m0 < 8; ++m0) {
                cmul(zr8[m0], zi8[m0], tr, ti);
                cmul(tr, ti, wA.x, wA.y);
            }
        }
        // ---- exchange 1 (wave-internal, XOR swizzle, no barrier) ----
        #pragma unroll
        for (int m0 = 0; m0 < 8; ++m0)
            ex2[g][64 * m0 + 8 * ((k1 ^ m0) & 7) + k2] = make_float2(zr8[m0], zi8[m0]);
        #pragma unroll
        for (int kk = 0; kk < 8; ++kk) {
            const float2 v = ex2[g][64 * k1 + 8 * ((kk ^ k1) & 7) + k2];
            zr8[kk] = v.x; zi8[kk] = v.y;
        }

        // ---- stage B: IDFT8 over the 8s digit, twiddle w512^(k2*(m0B+8*m1)) ----
        idft8(zr8, zi8);
        {
            float tr = wB0.x, ti = wB0.y;
            #pragma unroll
            for (int m1 = 0; m1 < 8; ++m1) {
                cmul(zr8[m1], zi8[m1], tr, ti);
                cmul(tr, ti, wBs.x, wBs.y);
            }
        }
        // ---- exchange 2 (wave-internal) ----
        #pragma unroll
        for (int m1 = 0; m1 < 8; ++m1)
            ex2[g][64 * k2 + 8 * ((m1 ^ k2) & 7) + k1] = make_float2(zr8[m1], zi8[m1]);
        #pragma unroll
        for (int kk = 0; kk < 8; ++kk) {
            const float2 v = ex2[g][64 * kk + 8 * ((k1 ^ kk) & 7) + k2];
            zr8[kk] = v.x; zi8[kk] = v.y;
        }

        // ---- stage C: IDFT8 over the 1s digit -> z[u + 64*m2] ----
        idft8(zr8, zi8);

        // ---- overlap-add, carry in registers (same thread owns both halves) ----
        if (t >= t0) {
            float2* orow = (float2*)(out + ((size_t)b * NROWS + (size_t)t) * 512);
            #pragma unroll
            for (int m = 0; m < 4; ++m)
                orow[u + 64 * m] = make_float2(zr8[m] + cc[m].x, zi8[m] + cc[m].y);
        }
        #pragma unroll
        for (int m = 0; m < 4; ++m) cc[m] = make_float2(zr8[m + 4], zi8[m + 4]);
    }
}

extern "C" void kernel_launch(void* const* d_in, const int* in_sizes, int n_in,
                              void* d_out, int out_size, void* d_ws, size_t ws_size,
                              hipStream_t stream) {
    const float* re = (const float*)d_in[0];
    const float* im = (const float*)d_in[1];
    float* out = (float*)d_out;
    dim3 grid(CHAINS_PER_BATCH / CPB, BATCH);
    istft_kernel<<<grid, 128, 0, stream>>>(re, im, out);
}

// Round 6
// 56.216 us; speedup vs baseline: 3.9819x; 3.9819x over previous
//
#include <hip/hip_runtime.h>
#include <math.h>

#define NBINS 513
#define NROWS 4000
#define BATCH 8
#define FPW   4                       // output rows per chain (one wave owns a chain)
#define CPB   2                       // chains (waves) per block
#define CHAINS_PER_BATCH (NROWS / FPW)   // 1000

__device__ __forceinline__ void cmul(float& ar, float& ai, float br, float bi) {
    const float t = ar * br - ai * bi;
    ai = ar * bi + ai * br;
    ar = t;
}

// In-place inverse DFT-8 (omega = e^{+2pi i/8}) on 8 complex register values.
__device__ __forceinline__ void idft8(float* xr, float* xi) {
    const float S = 0.70710678118654752440f;
    float er[4], ei[4], orr[4], oi[4];
    #pragma unroll
    for (int j = 0; j < 4; ++j) {
        er[j]  = xr[j] + xr[j+4];  ei[j] = xi[j] + xi[j+4];
        orr[j] = xr[j] - xr[j+4];  oi[j] = xi[j] - xi[j+4];
    }
    const float f1r = S * (orr[1] - oi[1]), f1i = S * (orr[1] + oi[1]);
    const float f2r = -oi[2],               f2i = orr[2];
    const float f3r = S * (-orr[3] - oi[3]), f3i = S * (orr[3] - oi[3]);
    {   // DFT4 (w4 = +i) over evens -> y0,y2,y4,y6
        const float eer = er[0]+er[2], eei = ei[0]+ei[2];
        const float eor = er[0]-er[2], eoi = ei[0]-ei[2];
        const float oer = er[1]+er[3], oei = ei[1]+ei[3];
        const float oor = er[1]-er[3], ooi = ei[1]-ei[3];
        xr[0] = eer + oer;  xi[0] = eei + oei;
        xr[2] = eor - ooi;  xi[2] = eoi + oor;
        xr[4] = eer - oer;  xi[4] = eei - oei;
        xr[6] = eor + ooi;  xi[6] = eoi - oor;
    }
    {   // DFT4 over odds*w8 -> y1,y3,y5,y7
        const float eer = orr[0]+f2r, eei = oi[0]+f2i;
        const float eor = orr[0]-f2r, eoi = oi[0]-f2i;
        const float oer = f1r+f3r,    oei = f1i+f3i;
        const float oor = f1r-f3r,    ooi = f1i-f3i;
        xr[1] = eer + oer;  xi[1] = eei + oei;
        xr[3] = eor - ooi;  xi[3] = eoi + oor;
        xr[5] = eer - oer;  xi[5] = eei - oei;
        xr[7] = eor + ooi;  xi[7] = eoi - oor;
    }
}

__global__ __launch_bounds__(128) void istft_kernel(
    const float* __restrict__ re, const float* __restrict__ im,
    float* __restrict__ out)
{
    __shared__ float2 ex2[CPB][512];   // wave-private exchange regions

    const int tid = threadIdx.x;
    const int u   = tid & 63;
    const int g   = tid >> 6;
    const int b   = blockIdx.y;
    const int chain = blockIdx.x * CPB + g;       // 0..999
    const int t0  = chain * FPW;

    const int k1 = u >> 3;
    const int k2 = u & 7;

    // ---- loop-invariant per-thread twiddles (registers, no LDS table) ----
    const float w0 = 6.283185307179586476925f / 1024.0f;
    float2 twp[8];
    #pragma unroll
    for (int j = 0; j < 8; ++j) {
        float s, c; sincosf(w0 * (float)(u + 64 * j), &s, &c);
        twp[j] = make_float2(c, s);
    }
    float2 wA, wB0, wBs;
    {
        float s, c;
        sincosf(w0 * (float)(16 * k1), &s, &c);     wA  = make_float2(c, s);
        sincosf(w0 * (float)(2 * k2 * k1), &s, &c); wB0 = make_float2(c, s);
        sincosf(w0 * (float)(16 * k2), &s, &c);     wBs = make_float2(c, s);
    }

    float2 cc[4];                      // OLA carry — wave-private registers
    #pragma unroll
    for (int m = 0; m < 4; ++m) cc[m] = make_float2(0.f, 0.f);

    for (int t = t0 - 1; t < t0 + FPW; ++t) {
        // ---- pack: Z[u+64j] = Xe + i*w1024^k*Xo, scaled by 0.5/1024 ----
        float zr8[8], zi8[8];
        if (t >= 0) {
            const size_t base = ((size_t)b * NROWS + (size_t)t) * NBINS;
            const float* rp = re + base;
            const float* ip = im + base;
            const float F = 4.8828125e-4f;   // 0.5 * (1/1024)
            #pragma unroll
            for (int j = 0; j < 8; ++j) {
                const int k = u + 64 * j;
                float xr = rp[k], xi = ip[k];
                float rc, ic;
                if (k == 0) { xi = 0.f; rc = rp[512]; ic = 0.f; }  // pocketfft c2r
                else        { rc = rp[512 - k]; ic = -ip[512 - k]; }
                const float er = F * (xr + rc), ei = F * (xi + ic);
                const float hr = F * (xr - rc), hi = F * (xi - ic);
                const float o_r = twp[j].x * hr - twp[j].y * hi;
                const float o_i = twp[j].x * hi + twp[j].y * hr;
                zr8[j] = er - o_i;
                zi8[j] = ei + o_r;
            }
        } else {
            #pragma unroll
            for (int j = 0; j < 8; ++j) { zr8[j] = 0.f; zi8[j] = 0.f; }
        }

        // ---- stage A: IDFT8 over the 64s digit, twiddle w64^(k1*m0) ----
        idft8(zr8, zi8);
        {
            float tr = wA.x, ti = wA.y;
            #pragma unroll
            for (int m0 = 1; m0 < 8; ++m0) {
                cmul(zr8[m0], zi8[m0], tr, ti);
                cmul(tr, ti, wA.x, wA.y);
            }
        }
        // ---- exchange 1 (wave-internal, XOR swizzle, no barrier) ----
        #pragma unroll
        for (int m0 = 0; m0 < 8; ++m0)
            ex2[g][64 * m0 + 8 * ((k1 ^ m0) & 7) + k2] = make_float2(zr8[m0], zi8[m0]);
        #pragma unroll
        for (int kk = 0; kk < 8; ++kk) {
            const float2 v = ex2[g][64 * k1 + 8 * ((kk ^ k1) & 7) + k2];
            zr8[kk] = v.x; zi8[kk] = v.y;
        }

        // ---- stage B: IDFT8 over the 8s digit, twiddle w512^(k2*(m0B+8*m1)) ----
        idft8(zr8, zi8);
        {
            float tr = wB0.x, ti = wB0.y;
            #pragma unroll
            for (int m1 = 0; m1 < 8; ++m1) {
                cmul(zr8[m1], zi8[m1], tr, ti);
                cmul(tr, ti, wBs.x, wBs.y);
            }
        }
        // ---- exchange 2 (wave-internal) ----
        #pragma unroll
        for (int m1 = 0; m1 < 8; ++m1)
            ex2[g][64 * k2 + 8 * ((m1 ^ k2) & 7) + k1] = make_float2(zr8[m1], zi8[m1]);
        #pragma unroll
        for (int kk = 0; kk < 8; ++kk) {
            const float2 v = ex2[g][64 * kk + 8 * ((k1 ^ kk) & 7) + k2];
            zr8[kk] = v.x; zi8[kk] = v.y;
        }

        // ---- stage C: IDFT8 over the 1s digit -> z[u + 64*m2] ----
        idft8(zr8, zi8);

        // ---- overlap-add, carry in registers (same thread owns both halves) ----
        if (t >= t0) {
            float2* orow = (float2*)(out + ((size_t)b * NROWS + (size_t)t) * 512);
            #pragma unroll
            for (int m = 0; m < 4; ++m)
                orow[u + 64 * m] = make_float2(zr8[m] + cc[m].x, zi8[m] + cc[m].y);
        }
        #pragma unroll
        for (int m = 0; m < 4; ++m) cc[m] = make_float2(zr8[m + 4], zi8[m + 4]);
    }
}

extern "C" void kernel_launch(void* const* d_in, const int* in_sizes, int n_in,
                              void* d_out, int out_size, void* d_ws, size_t ws_size,
                              hipStream_t stream) {
    const float* re = (const float*)d_in[0];
    const float* im = (const float*)d_in[1];
    float* out = (float*)d_out;
    dim3 grid(CHAINS_PER_BATCH / CPB, BATCH);
    istft_kernel<<<grid, 128, 0, stream>>>(re, im, out);
}

// Round 7
// 46.324 us; speedup vs baseline: 4.8321x; 1.2135x over previous
//
#include <hip/hip_runtime.h>
#include <math.h>

#define NBINS 513
#define NROWS 4000
#define BATCH 8
#define FPW   8                          // output rows per chain (1 wave = 1 chain)
#define CHAINS_PER_BATCH (NROWS / FPW)   // 500

__device__ __forceinline__ void cmul(float& ar, float& ai, float br, float bi) {
    const float t = ar * br - ai * bi;
    ai = ar * bi + ai * br;
    ar = t;
}

// In-place inverse DFT-8 (omega = e^{+2pi i/8}) on 8 complex register values.
__device__ __forceinline__ void idft8(float* xr, float* xi) {
    const float S = 0.70710678118654752440f;
    float er[4], ei[4], orr[4], oi[4];
    #pragma unroll
    for (int j = 0; j < 4; ++j) {
        er[j]  = xr[j] + xr[j+4];  ei[j] = xi[j] + xi[j+4];
        orr[j] = xr[j] - xr[j+4];  oi[j] = xi[j] - xi[j+4];
    }
    const float f1r = S * (orr[1] - oi[1]), f1i = S * (orr[1] + oi[1]);
    const float f2r = -oi[2],               f2i = orr[2];
    const float f3r = S * (-orr[3] - oi[3]), f3i = S * (orr[3] - oi[3]);
    {   // DFT4 (w4 = +i) over evens -> y0,y2,y4,y6
        const float eer = er[0]+er[2], eei = ei[0]+ei[2];
        const float eor = er[0]-er[2], eoi = ei[0]-ei[2];
        const float oer = er[1]+er[3], oei = ei[1]+ei[3];
        const float oor = er[1]-er[3], ooi = ei[1]-ei[3];
        xr[0] = eer + oer;  xi[0] = eei + oei;
        xr[2] = eor - ooi;  xi[2] = eoi + oor;
        xr[4] = eer - oer;  xi[4] = eei - oei;
        xr[6] = eor + ooi;  xi[6] = eoi - oor;
    }
    {   // DFT4 over odds*w8 -> y1,y3,y5,y7
        const float eer = orr[0]+f2r, eei = oi[0]+f2i;
        const float eor = orr[0]-f2r, eoi = oi[0]-f2i;
        const float oer = f1r+f3r,    oei = f1i+f3i;
        const float oor = f1r-f3r,    ooi = f1i-f3i;
        xr[1] = eer + oer;  xi[1] = eei + oei;
        xr[3] = eor - ooi;  xi[3] = eoi + oor;
        xr[5] = eer - oer;  xi[5] = eei - oei;
        xr[7] = eor + ooi;  xi[7] = eoi - oor;
    }
}

__global__ __launch_bounds__(64) void istft_kernel(
    const float* __restrict__ re, const float* __restrict__ im,
    float* __restrict__ out)
{
    __shared__ float2 ex2[512];        // wave-private exchange region (1 wave/block)

    const int u  = threadIdx.x;        // 0..63
    const int b  = blockIdx.y;
    const int t0 = blockIdx.x * FPW;

    const int k1 = u >> 3;
    const int k2 = u & 7;

    // ---- loop-invariant per-thread twiddles (registers) ----
    const float w0 = 6.283185307179586476925f / 1024.0f;
    float2 twp[8];
    #pragma unroll
    for (int j = 0; j < 8; ++j) {
        float s, c; sincosf(w0 * (float)(u + 64 * j), &s, &c);
        twp[j] = make_float2(c, s);
    }
    float2 wA, wB0, wBs;
    {
        float s, c;
        sincosf(w0 * (float)(16 * k1), &s, &c);     wA  = make_float2(c, s);
        sincosf(w0 * (float)(2 * k2 * k1), &s, &c); wB0 = make_float2(c, s);
        sincosf(w0 * (float)(16 * k2), &s, &c);     wBs = make_float2(c, s);
    }

    float2 cc[4];                      // OLA carry (registers)
    #pragma unroll
    for (int m = 0; m < 4; ++m) cc[m] = make_float2(0.f, 0.f);

    // ---- prefetch registers: raw inputs of the NEXT frame ----
    float pxr[8], pxi[8], pmr[8], pmi[8];

    auto issue_loads = [&](int t) {
        if (t >= 0) {                  // t < NROWS guaranteed within a chain
            const size_t base = ((size_t)b * NROWS + (size_t)t) * NBINS;
            const float* rp = re + base;
            const float* ip = im + base;
            #pragma unroll
            for (int j = 0; j < 8; ++j) {
                const int k = u + 64 * j;
                pxr[j] = rp[k];        pxi[j] = ip[k];
                pmr[j] = rp[512 - k];  pmi[j] = ip[512 - k];   // k=0 -> bin 512
            }
        } else {
            #pragma unroll
            for (int j = 0; j < 8; ++j) { pxr[j]=0.f; pxi[j]=0.f; pmr[j]=0.f; pmi[j]=0.f; }
        }
    };

    issue_loads(t0 - 1);               // priming frame

    for (int t = t0 - 1; t < t0 + FPW; ++t) {
        // ---- pack from prefetched regs: Z[u+64j], scaled by 0.5/1024 ----
        float zr8[8], zi8[8];
        {
            const float F = 4.8828125e-4f;   // 0.5 * (1/1024)
            #pragma unroll
            for (int j = 0; j < 8; ++j) {
                const int k = u + 64 * j;
                float xr = pxr[j], xi = pxi[j];
                float rc = pmr[j], ic = -pmi[j];
                if (k == 0) { xi = 0.f; ic = 0.f; }   // pocketfft c2r: Im ignored
                const float er = F * (xr + rc), ei = F * (xi + ic);
                const float hr = F * (xr - rc), hi = F * (xi - ic);
                const float o_r = twp[j].x * hr - twp[j].y * hi;
                const float o_i = twp[j].x * hi + twp[j].y * hr;
                zr8[j] = er - o_i;
                zi8[j] = ei + o_r;
            }
        }

        // ---- issue next frame's loads; latency hides under the FFT below ----
        if (t + 1 < t0 + FPW) issue_loads(t + 1);

        // ---- stage A: IDFT8 over the 64s digit, twiddle w64^(k1*m0) ----
        idft8(zr8, zi8);
        {
            float tr = wA.x, ti = wA.y;
            #pragma unroll
            for (int m0 = 1; m0 < 8; ++m0) {
                cmul(zr8[m0], zi8[m0], tr, ti);
                cmul(tr, ti, wA.x, wA.y);
            }
        }
        // ---- exchange 1 (wave-internal, XOR swizzle, no barrier) ----
        #pragma unroll
        for (int m0 = 0; m0 < 8; ++m0)
            ex2[64 * m0 + 8 * ((k1 ^ m0) & 7) + k2] = make_float2(zr8[m0], zi8[m0]);
        #pragma unroll
        for (int kk = 0; kk < 8; ++kk) {
            const float2 v = ex2[64 * k1 + 8 * ((kk ^ k1) & 7) + k2];
            zr8[kk] = v.x; zi8[kk] = v.y;
        }

        // ---- stage B: IDFT8 over the 8s digit, twiddle w512^(k2*(m0B+8*m1)) ----
        idft8(zr8, zi8);
        {
            float tr = wB0.x, ti = wB0.y;
            #pragma unroll
            for (int m1 = 0; m1 < 8; ++m1) {
                cmul(zr8[m1], zi8[m1], tr, ti);
                cmul(tr, ti, wBs.x, wBs.y);
            }
        }
        // ---- exchange 2 (wave-internal) ----
        #pragma unroll
        for (int m1 = 0; m1 < 8; ++m1)
            ex2[64 * k2 + 8 * ((m1 ^ k2) & 7) + k1] = make_float2(zr8[m1], zi8[m1]);
        #pragma unroll
        for (int kk = 0; kk < 8; ++kk) {
            const float2 v = ex2[64 * kk + 8 * ((k1 ^ kk) & 7) + k2];
            zr8[kk] = v.x; zi8[kk] = v.y;
        }

        // ---- stage C: IDFT8 over the 1s digit -> z[u + 64*m2] ----
        idft8(zr8, zi8);

        // ---- overlap-add, carry in registers ----
        if (t >= t0) {
            float2* orow = (float2*)(out + ((size_t)b * NROWS + (size_t)t) * 512);
            #pragma unroll
            for (int m = 0; m < 4; ++m)
                orow[u + 64 * m] = make_float2(zr8[m] + cc[m].x, zi8[m] + cc[m].y);
        }
        #pragma unroll
        for (int m = 0; m < 4; ++m) cc[m] = make_float2(zr8[m + 4], zi8[m + 4]);
    }
}

extern "C" void kernel_launch(void* const* d_in, const int* in_sizes, int n_in,
                              void* d_out, int out_size, void* d_ws, size_t ws_size,
                              hipStream_t stream) {
    const float* re = (const float*)d_in[0];
    const float* im = (const float*)d_in[1];
    float* out = (float*)d_out;
    dim3 grid(CHAINS_PER_BATCH, BATCH);
    istft_kernel<<<grid, 64, 0, stream>>>(re, im, out);
}